// Round 11
// baseline (705.666 us; speedup 1.0000x reference)
//
#include <hip/hip_runtime.h>

#define N_NODES 50000
#define N_PAD   50048          // 391 * 128
#define N_EDGES 800000
#define N_REL   8
#define NSEG    (N_REL * N_NODES)      // 400000
#define SCAN_NB 391                    // ceil(NSEG / 1024)
#define NSTRIPE 391                    // 128-row stripes
#define SPX     49                     // ceil(391/8) stripes per XCD

typedef short bf16x8 __attribute__((ext_vector_type(8)));
typedef float f32x4  __attribute__((ext_vector_type(4)));

__device__ __forceinline__ ushort f2bf(float f) {
    union { float f; unsigned u; } c; c.f = f;
    unsigned u = c.u + 0x7fffu + ((c.u >> 16) & 1u);   // RNE
    return (ushort)(u >> 16);
}
__device__ __forceinline__ void add8(float* s, uint4 v) {
    unsigned u[4] = {v.x, v.y, v.z, v.w};
    #pragma unroll
    for (int k = 0; k < 4; ++k) {
        s[2 * k]     += __uint_as_float(u[k] << 16);
        s[2 * k + 1] += __uint_as_float(u[k] & 0xffff0000u);
    }
}
__device__ __forceinline__ void fma8(float* s, uint4 v, float w) {
    unsigned u[4] = {v.x, v.y, v.z, v.w};
    #pragma unroll
    for (int k = 0; k < 4; ++k) {
        s[2 * k]     = fmaf(__uint_as_float(u[k] << 16),        w, s[2 * k]);
        s[2 * k + 1] = fmaf(__uint_as_float(u[k] & 0xffff0000u), w, s[2 * k + 1]);
    }
}
__device__ __forceinline__ void async16(const ushort* g, ushort* l) {
    __builtin_amdgcn_global_load_lds((const __attribute__((address_space(1))) void*)g,
                                     (__attribute__((address_space(3))) void*)l, 16, 0, 0);
}

// ---------------- edge preprocessing: counting sort by (dst*R + rel) ----------------
// dst-major key: each dst owns ONE contiguous run of ~16 edges -> gather is a single
// flat loop with high MLP. sorted[pos] packs {src:17b | rel:3b | segment_count:12b}.

__global__ void count_edges(const int* __restrict__ dst, const int* __restrict__ et,
                            int* __restrict__ cnt) {
    int e = blockIdx.x * 256 + threadIdx.x;
    if (e < N_EDGES) atomicAdd(&cnt[dst[e] * N_REL + et[e]], 1);
}

__global__ __launch_bounds__(256) void scan_pass1(const int* __restrict__ cnt,
                                                  int* __restrict__ sums) {
    __shared__ int sc[256];
    int b = blockIdx.x, t = threadIdx.x;
    int base = b * 1024 + t * 4;
    int v = 0;
    #pragma unroll
    for (int i = 0; i < 4; ++i) { int idx = base + i; if (idx < NSEG) v += cnt[idx]; }
    sc[t] = v; __syncthreads();
    for (int off = 1; off < 256; off <<= 1) {
        int x = (t >= off) ? sc[t - off] : 0;
        __syncthreads(); sc[t] += x; __syncthreads();
    }
    if (t == 255) sums[b] = sc[255];
}

__global__ __launch_bounds__(512) void scan_pass2(int* __restrict__ sums, int nb) {
    __shared__ int sc[512];
    int t = threadIdx.x;
    int v = (t < nb) ? sums[t] : 0;
    sc[t] = v; __syncthreads();
    for (int off = 1; off < 512; off <<= 1) {
        int x = (t >= off) ? sc[t - off] : 0;
        __syncthreads(); sc[t] += x; __syncthreads();
    }
    if (t < nb) sums[t] = sc[t] - v;     // exclusive
}

__global__ __launch_bounds__(256) void scan_pass3(const int* __restrict__ cnt,
                                                  const int* __restrict__ sums,
                                                  int* __restrict__ row_ptr) {
    __shared__ int sc[256];
    int b = blockIdx.x, t = threadIdx.x;
    int base = b * 1024 + t * 4;
    int e[4]; int v = 0;
    #pragma unroll
    for (int i = 0; i < 4; ++i) { int idx = base + i; e[i] = (idx < NSEG) ? cnt[idx] : 0; v += e[i]; }
    sc[t] = v; __syncthreads();
    for (int off = 1; off < 256; off <<= 1) {
        int x = (t >= off) ? sc[t - off] : 0;
        __syncthreads(); sc[t] += x; __syncthreads();
    }
    int run = sums[b] + (sc[t] - v);
    #pragma unroll
    for (int i = 0; i < 4; ++i) {
        int idx = base + i;
        if (idx < NSEG) row_ptr[idx] = run;
        run += e[i];
    }
    if (b == 0 && t == 0) row_ptr[NSEG] = N_EDGES;
}

// cnt doubles as the placement cursor (atomicSub); cnt is dead afterwards.
__global__ void place_edges(const int* __restrict__ src, const int* __restrict__ dst,
                            const int* __restrict__ et, const int* __restrict__ row_ptr,
                            int* __restrict__ cnt, int* __restrict__ sorted) {
    int e = blockIdx.x * 256 + threadIdx.x;
    if (e >= N_EDGES) return;
    int r = et[e];
    int key = dst[e] * N_REL + r;
    int old = atomicSub(&cnt[key], 1);
    int r0 = row_ptr[key];
    int c = row_ptr[key + 1] - r0;                 // |N_r(dst)| for this segment
    sorted[r0 + old - 1] = src[e] | (r << 17) | (c << 20);
}

// ---------------- weight packs ----------------
// L4 layout: BT[col][k], col = r*O+o (r=8 -> root), zero-pad cols to NPAD.
__global__ void convert_weights(const float* __restrict__ W, const float* __restrict__ root,
                                ushort* __restrict__ BT, int K, int O, int NPAD) {
    int idx = blockIdx.x * 256 + threadIdx.x;
    if (idx >= NPAD * K) return;
    int col = idx / K, i = idx % K;
    float v = 0.0f;
    if (col < N_REL * O) {
        int r = col / O, o = col % O;
        v = W[((size_t)r * K + i) * O + o];
    } else if (col < (N_REL + 1) * O) {
        v = root[(size_t)i * O + (col - N_REL * O)];
    }
    BT[idx] = f2bf(v);
}

// Split layout (L1..3, O=256 in two 128-col halves): BT[half][col][k], col 0..1151;
// col<1024 -> W_{col/128}[k][half*128 + col%128]; col>=1024 -> root[k][half*128+col-1024].
// 1152 = 9*128 exactly, no zero padding.
__global__ void convert_weights_split(const float* __restrict__ W, const float* __restrict__ root,
                                      ushort* __restrict__ BT, int K) {
    int idx = blockIdx.x * 256 + threadIdx.x;
    if (idx >= 2304 * K) return;
    int col = idx / K, i = idx % K;
    int half = col / 1152, ch = col % 1152;
    float v;
    if (ch < 1024) {
        int r = ch / 128, o = half * 128 + (ch & 127);
        v = W[((size_t)r * K + i) * 256 + o];
    } else {
        v = root[(size_t)i * 256 + half * 128 + (ch - 1024)];
    }
    BT[idx] = f2bf(v);
}

__global__ void f32_to_bf16(const float* __restrict__ in, ushort* __restrict__ out, int n4) {
    int i = blockIdx.x * 256 + threadIdx.x;
    if (i >= n4) return;
    float4 v = ((const float4*)in)[i];
    ushort4 s; s.x = f2bf(v.x); s.y = f2bf(v.y); s.z = f2bf(v.z); s.w = f2bf(v.w);
    ((ushort4*)out)[i] = s;
}

// ---------------- bf16 MFMA GEMM: 2-phase double-buffered k-loop (round-4 proven) ----------------
template<int K, int CTS, int NW>
__global__ __launch_bounds__(256)
void gemm_mfma(const ushort* __restrict__ A, const ushort* __restrict__ BT,
               ushort* __restrict__ Y) {
    // ---- swizzle: f -> (stripe y, col-tile ct) pinned to XCD f&7 ----
    const int f = blockIdx.x;
    const int g = f & 7, m = f >> 3;
    const int y = g + 8 * (m / CTS);
    const int ct = m % CTS;
    if (y >= NSTRIPE) return;               // uniform early-exit (before any barrier)
    const int row0 = y * 128;
    const int col0 = ct * 128;

    __shared__ ushort SMEM[16384];          // 32 KB: 2 x (As|Bs 16 KB); epilogue Ts aliases head
    const int t = threadIdx.x;
    const int lane = t & 63;
    const int w = t >> 6;
    const int l16 = lane & 15, q = lane >> 4;
    const int wm = (w & 1) * 64, wn = (w >> 1) * 64;

    const int c0i = w * 64 + lane;
    const int c1i = c0i + 256;
    const int r0i = c0i >> 2, r1i = c1i >> 2;
    const int j0i = (c0i & 3) ^ ((r0i >> 1) & 3);
    const int j1i = (c1i & 3) ^ ((r1i >> 1) & 3);
    const size_t ga0 = (size_t)r0i * K + (size_t)j0i * 8;
    const size_t ga1 = (size_t)r1i * K + (size_t)j1i * 8;
    const ushort* Ab = A + (size_t)row0 * K;
    const ushort* Bb = BT + (size_t)col0 * K;

    const int qx = (q ^ ((l16 >> 1) & 3)) * 8;   // un-swizzle chunk on LDS read

    f32x4 acc[4][4] = {};

    auto STAGE = [&](int b, int k0) {
        ushort* As = SMEM + b * 8192;
        ushort* Bs = As + 4096;
        async16(Ab + k0 + ga0, &As[w * 512]);
        async16(Ab + k0 + ga1, &As[(w + 4) * 512]);
        async16(Bb + k0 + ga0, &Bs[w * 512]);
        async16(Bb + k0 + ga1, &Bs[(w + 4) * 512]);
    };
    auto COMPUTE = [&](int b) {
        ushort* As = SMEM + b * 8192;
        ushort* Bs = As + 4096;
        bf16x8 a[4], bb[4];
        #pragma unroll
        for (int i = 0; i < 4; ++i) {
            a[i]  = *(const bf16x8*)&As[(wm + i * 16 + l16) * 32 + qx];
            bb[i] = *(const bf16x8*)&Bs[(wn + i * 16 + l16) * 32 + qx];
        }
        #pragma unroll
        for (int i = 0; i < 4; ++i)
            #pragma unroll
            for (int j = 0; j < 4; ++j)
                acc[i][j] = __builtin_amdgcn_mfma_f32_16x16x32_bf16(a[i], bb[j], acc[i][j], 0, 0, 0);
    };

    constexpr int NSTEP = K / 32;
    STAGE(0, 0);
    __syncthreads();                        // prologue drain (first tile staged)
    #pragma unroll
    for (int s = 0; s < NSTEP; ++s) {
        if (s + 1 < NSTEP) STAGE((s + 1) & 1, 32 * (s + 1));   // prefetch next tile
        COMPUTE(s & 1);                                         // compute current
        __syncthreads();   // implicit vmcnt(0): next tile landed (hidden under MFMA)
    }

    // ---- epilogue: two-pass transpose via wave-private LDS (32 rows x stride 72),
    // then full-line stores: 8 lanes cover 128 B of one row per instruction.
    ushort* Ts = &SMEM[w * 32 * 72];
    const int rr = lane >> 3;               // 0..7 row within 8-row group
    const int cc = (lane & 7) * 8;          // 16B chunk within row
    #pragma unroll
    for (int half = 0; half < 2; ++half) {
        // scatter: D mapping col=l16, row=q*4+reg (verified gfx950 layout)
        #pragma unroll
        for (int i = 0; i < 2; ++i)
            #pragma unroll
            for (int j = 0; j < 4; ++j)
                #pragma unroll
                for (int r = 0; r < 4; ++r)
                    Ts[(i * 16 + q * 4 + r) * 72 + j * 16 + l16] = f2bf(acc[half * 2 + i][j][r]);
        // gather+store (wave-private region; compiler orders LDS ops via lgkmcnt)
        #pragma unroll
        for (int p = 0; p < 4; ++p) {
            int row = p * 8 + rr;           // 0..31 local
            uint4 v = *(const uint4*)&Ts[row * 72 + cc];
            *(uint4*)(Y + (size_t)(row0 + wm + half * 32 + row) * NW + col0 + wn + cc) = v;
        }
    }
}

// ---------------- fused gather: out[d] = act( root + bias + sum_e w_e * Y[src_e, rel_e*O+c] ) ----------------
// O = per-relation slice width in Y (128 for split halves, 64 for L4); OSTRIDE = row
// stride of the output (256 for the H buffers, 64 for L4 f32 out). Caller offsets
// bias/out pointers by the half's column base. 8-wide MLP loop (round-10 proven).
template<int O, int OSTRIDE>
__global__ __launch_bounds__(256)
void gather_kernel(const ushort* __restrict__ Y, int NW,
                   const int* __restrict__ row_ptr, const int* __restrict__ sorted,
                   const float* __restrict__ bias,
                   float* __restrict__ out_f32, ushort* __restrict__ out_bf16, int relu) {
    constexpr int TPN = O / 8;
    int d = blockIdx.x * (256 / TPN) + threadIdx.x / TPN;
    if (d >= N_NODES) return;
    int c0 = (threadIdx.x % TPN) * 8;
    int p0 = row_ptr[d * N_REL];
    int p1 = row_ptr[d * N_REL + N_REL];
    float sum[8] = {};
    add8(sum, *(const uint4*)(Y + (size_t)d * NW + N_REL * O + c0));   // root slice
    #pragma unroll
    for (int k = 0; k < 8; ++k) sum[k] += bias[c0 + k];
    const ushort* Yc = Y + c0;
    #define EDGE_LD(sx) (*(const uint4*)(Yc + (size_t)((sx) & 0x1FFFF) * NW + ((((sx) >> 17) & 7) * O)))
    #define EDGE_W(sx)  (1.0f / (float)((unsigned)(sx) >> 20))
    int e = p0;
    for (; e + 8 <= p1; e += 8) {
        int s0 = sorted[e],     s1 = sorted[e + 1], s2 = sorted[e + 2], s3 = sorted[e + 3];
        int s4 = sorted[e + 4], s5 = sorted[e + 5], s6 = sorted[e + 6], s7 = sorted[e + 7];
        uint4 v0 = EDGE_LD(s0);
        uint4 v1 = EDGE_LD(s1);
        uint4 v2 = EDGE_LD(s2);
        uint4 v3 = EDGE_LD(s3);
        uint4 v4 = EDGE_LD(s4);
        uint4 v5 = EDGE_LD(s5);
        uint4 v6 = EDGE_LD(s6);
        uint4 v7 = EDGE_LD(s7);
        fma8(sum, v0, EDGE_W(s0));
        fma8(sum, v1, EDGE_W(s1));
        fma8(sum, v2, EDGE_W(s2));
        fma8(sum, v3, EDGE_W(s3));
        fma8(sum, v4, EDGE_W(s4));
        fma8(sum, v5, EDGE_W(s5));
        fma8(sum, v6, EDGE_W(s6));
        fma8(sum, v7, EDGE_W(s7));
    }
    if (e + 4 <= p1) {
        int s0 = sorted[e], s1 = sorted[e + 1], s2 = sorted[e + 2], s3 = sorted[e + 3];
        uint4 v0 = EDGE_LD(s0);
        uint4 v1 = EDGE_LD(s1);
        uint4 v2 = EDGE_LD(s2);
        uint4 v3 = EDGE_LD(s3);
        fma8(sum, v0, EDGE_W(s0));
        fma8(sum, v1, EDGE_W(s1));
        fma8(sum, v2, EDGE_W(s2));
        fma8(sum, v3, EDGE_W(s3));
        e += 4;
    }
    for (; e < p1; ++e) {
        int s = sorted[e];
        uint4 v = EDGE_LD(s);
        fma8(sum, v, EDGE_W(s));
    }
    #undef EDGE_LD
    #undef EDGE_W
    if (relu) {
        #pragma unroll
        for (int k = 0; k < 8; ++k) sum[k] = fmaxf(sum[k], 0.0f);
    }
    if (out_bf16) {
        ushort o[8];
        #pragma unroll
        for (int k = 0; k < 8; ++k) o[k] = f2bf(sum[k]);
        *(uint4*)(out_bf16 + (size_t)d * OSTRIDE + c0) = *(const uint4*)o;
    } else {
        float* p = out_f32 + (size_t)d * OSTRIDE + c0;
        *(float4*)p = make_float4(sum[0], sum[1], sum[2], sum[3]);
        *(float4*)(p + 4) = make_float4(sum[4], sum[5], sum[6], sum[7]);
    }
}

// ---------------- host side ----------------

extern "C" void kernel_launch(void* const* d_in, const int* in_sizes, int n_in,
                              void* d_out, int out_size, void* d_ws, size_t ws_size,
                              hipStream_t stream) {
    const float* x  = (const float*)d_in[0];
    const int*   ei = (const int*)d_in[1];
    const int*   et = (const int*)d_in[2];
    const float* W[4]  = {(const float*)d_in[3], (const float*)d_in[6], (const float*)d_in[9],  (const float*)d_in[12]};
    const float* RT[4] = {(const float*)d_in[4], (const float*)d_in[7], (const float*)d_in[10], (const float*)d_in[13]};
    const float* BI[4] = {(const float*)d_in[5], (const float*)d_in[8], (const float*)d_in[11], (const float*)d_in[14]};
    const int* src = ei;
    const int* dst = ei + N_EDGES;

    // ---- workspace carve-up (~187 MB, well under proven 264 MB) ----
    char* ws = (char*)d_ws;
    size_t off = 0;
    auto take = [&](size_t bytes) -> char* {
        char* p = ws + off;
        off = (off + bytes + 255) & ~(size_t)255;
        return p;
    };
    int* row_ptr = (int*)take((size_t)(NSEG + 1) * 4);
    int* sorted  = (int*)take((size_t)N_EDGES * 4);
    ushort* BT1 = (ushort*)take((size_t)2304 * 128 * 2);   // split layout [2][1152][128]
    ushort* BT2 = (ushort*)take((size_t)2304 * 256 * 2);   // split layout [2][1152][256]
    ushort* BT3 = (ushort*)take((size_t)2304 * 256 * 2);
    ushort* BT4 = (ushort*)take((size_t)640 * 256 * 2);    // L4 old layout
    ushort* X0  = (ushort*)take((size_t)N_PAD * 128 * 2);  // bf16 input
    ushort* Ha  = (ushort*)take((size_t)N_PAD * 256 * 2);
    ushort* Hb  = (ushort*)take((size_t)N_PAD * 256 * 2);
    ushort* Yb  = (ushort*)take((size_t)N_PAD * 1152 * 2); // 115 MB half-width Y (L3-fit)
    // cnt + sums alias the head of Yb: dead before the first GEMM writes Yb.
    int* cnt  = (int*)Yb;
    int* sums = (int*)((char*)Yb + (size_t)NSEG * 4);

    // ---- edge preprocessing (once per call) ----
    hipMemsetAsync(cnt, 0, (size_t)NSEG * 4, stream);
    count_edges<<<(N_EDGES + 255) / 256, 256, 0, stream>>>(dst, et, cnt);
    scan_pass1<<<SCAN_NB, 256, 0, stream>>>(cnt, sums);
    scan_pass2<<<1, 512, 0, stream>>>(sums, SCAN_NB);
    scan_pass3<<<SCAN_NB, 256, 0, stream>>>(cnt, sums, row_ptr);
    place_edges<<<(N_EDGES + 255) / 256, 256, 0, stream>>>(src, dst, et, row_ptr, cnt, sorted);

    // ---- weight packs ----
    convert_weights_split<<<(2304 * 128 + 255) / 256, 256, 0, stream>>>(W[0], RT[0], BT1, 128);
    convert_weights_split<<<(2304 * 256 + 255) / 256, 256, 0, stream>>>(W[1], RT[1], BT2, 256);
    convert_weights_split<<<(2304 * 256 + 255) / 256, 256, 0, stream>>>(W[2], RT[2], BT3, 256);
    convert_weights<<<(640 * 256 + 255) / 256, 256, 0, stream>>>(W[3], RT[3], BT4, 256, 64, 640);

    // ---- input to bf16 ----
    f32_to_bf16<<<(N_NODES * 128 / 4 + 255) / 256, 256, 0, stream>>>(x, X0, N_NODES * 128 / 4);

    // ---- layers 1-3: two 128-col halves each; Y_half (115 MB) stays L3-resident
    // between its GEMM (producer) and gather (consumer) ----
    const int G9 = 8 * SPX * 9;     // 3528 blocks: 391 stripes x 9 col-tiles
    const int GH = N_NODES / 16;    // 3125: gather<128> grid (16 nodes/block)

    // L1: X0 (K=128) -> Ha
    gemm_mfma<128, 9, 1152><<<G9, 256, 0, stream>>>(X0, BT1, Yb);
    gather_kernel<128, 256><<<GH, 256, 0, stream>>>(Yb, 1152, row_ptr, sorted, BI[0], nullptr, Ha, 1);
    gemm_mfma<128, 9, 1152><<<G9, 256, 0, stream>>>(X0, BT1 + (size_t)1152 * 128, Yb);
    gather_kernel<128, 256><<<GH, 256, 0, stream>>>(Yb, 1152, row_ptr, sorted, BI[0] + 128, nullptr, Ha + 128, 1);

    // L2: Ha -> Hb
    gemm_mfma<256, 9, 1152><<<G9, 256, 0, stream>>>(Ha, BT2, Yb);
    gather_kernel<128, 256><<<GH, 256, 0, stream>>>(Yb, 1152, row_ptr, sorted, BI[1], nullptr, Hb, 1);
    gemm_mfma<256, 9, 1152><<<G9, 256, 0, stream>>>(Ha, BT2 + (size_t)1152 * 256, Yb);
    gather_kernel<128, 256><<<GH, 256, 0, stream>>>(Yb, 1152, row_ptr, sorted, BI[1] + 128, nullptr, Hb + 128, 1);

    // L3: Hb -> Ha
    gemm_mfma<256, 9, 1152><<<G9, 256, 0, stream>>>(Hb, BT3, Yb);
    gather_kernel<128, 256><<<GH, 256, 0, stream>>>(Yb, 1152, row_ptr, sorted, BI[2], nullptr, Ha, 1);
    gemm_mfma<256, 9, 1152><<<G9, 256, 0, stream>>>(Hb, BT3 + (size_t)1152 * 256, Yb);
    gather_kernel<128, 256><<<GH, 256, 0, stream>>>(Yb, 1152, row_ptr, sorted, BI[2] + 128, nullptr, Ha + 128, 1);

    // ---- layer 4: Ha -> out (Y width 640 = 64 MB, already L3-friendly) ----
    const int G5 = 8 * SPX * 5;     // 1960
    gemm_mfma<256, 5, 640><<<G5, 256, 0, stream>>>(Ha, BT4, Yb);
    gather_kernel<64, 64><<<dim3((N_NODES + 31) / 32), 256, 0, stream>>>(
        Yb, 640, row_ptr, sorted, BI[3], (float*)d_out, nullptr, 0);
}

// Round 12
// 659.190 us; speedup vs baseline: 1.0705x; 1.0705x over previous
//
#include <hip/hip_runtime.h>

#define N_NODES 50000
#define N_PAD   50048          // 391 * 128
#define N_EDGES 800000
#define N_REL   8
#define NSEG    (N_REL * N_NODES)      // 400000
#define SCAN_NB 391                    // ceil(NSEG / 1024)
#define NSTRIPE 391                    // 128-row stripes
#define SPX     49                     // ceil(391/8) stripes per XCD

typedef short bf16x8 __attribute__((ext_vector_type(8)));
typedef float f32x4  __attribute__((ext_vector_type(4)));

__device__ __forceinline__ ushort f2bf(float f) {
    union { float f; unsigned u; } c; c.f = f;
    unsigned u = c.u + 0x7fffu + ((c.u >> 16) & 1u);   // RNE
    return (ushort)(u >> 16);
}
__device__ __forceinline__ void add8(float* s, uint4 v) {
    unsigned u[4] = {v.x, v.y, v.z, v.w};
    #pragma unroll
    for (int k = 0; k < 4; ++k) {
        s[2 * k]     += __uint_as_float(u[k] << 16);
        s[2 * k + 1] += __uint_as_float(u[k] & 0xffff0000u);
    }
}
__device__ __forceinline__ void fma8(float* s, uint4 v, float w) {
    unsigned u[4] = {v.x, v.y, v.z, v.w};
    #pragma unroll
    for (int k = 0; k < 4; ++k) {
        s[2 * k]     = fmaf(__uint_as_float(u[k] << 16),        w, s[2 * k]);
        s[2 * k + 1] = fmaf(__uint_as_float(u[k] & 0xffff0000u), w, s[2 * k + 1]);
    }
}
__device__ __forceinline__ void async16(const ushort* g, ushort* l) {
    __builtin_amdgcn_global_load_lds((const __attribute__((address_space(1))) void*)g,
                                     (__attribute__((address_space(3))) void*)l, 16, 0, 0);
}

// ---------------- edge preprocessing: counting sort by (dst*R + rel) ----------------
// dst-major key: each dst owns ONE contiguous run of ~16 edges -> gather is a single
// flat loop with high MLP. sorted[pos] packs {src:17b | rel:3b | segment_count:12b}.

// Fused: bf16 input convert + edge histogram (independent streams, disjoint outputs;
// one launch instead of two -- preprocessing is launch-overhead-bound, ~4 us/launch).
__global__ void f2bf_and_count(const float* __restrict__ in, ushort* __restrict__ out, int n4,
                               const int* __restrict__ dst, const int* __restrict__ et,
                               int* __restrict__ cnt) {
    int i = blockIdx.x * 256 + threadIdx.x;
    if (i < n4) {
        float4 v = ((const float4*)in)[i];
        ushort4 s; s.x = f2bf(v.x); s.y = f2bf(v.y); s.z = f2bf(v.z); s.w = f2bf(v.w);
        ((ushort4*)out)[i] = s;
    }
    if (i < N_EDGES) atomicAdd(&cnt[dst[i] * N_REL + et[i]], 1);
}

__global__ __launch_bounds__(256) void scan_pass1(const int* __restrict__ cnt,
                                                  int* __restrict__ sums) {
    __shared__ int sc[256];
    int b = blockIdx.x, t = threadIdx.x;
    int base = b * 1024 + t * 4;
    int v = 0;
    #pragma unroll
    for (int i = 0; i < 4; ++i) { int idx = base + i; if (idx < NSEG) v += cnt[idx]; }
    sc[t] = v; __syncthreads();
    for (int off = 1; off < 256; off <<= 1) {
        int x = (t >= off) ? sc[t - off] : 0;
        __syncthreads(); sc[t] += x; __syncthreads();
    }
    if (t == 255) sums[b] = sc[255];
}

__global__ __launch_bounds__(512) void scan_pass2(int* __restrict__ sums, int nb) {
    __shared__ int sc[512];
    int t = threadIdx.x;
    int v = (t < nb) ? sums[t] : 0;
    sc[t] = v; __syncthreads();
    for (int off = 1; off < 512; off <<= 1) {
        int x = (t >= off) ? sc[t - off] : 0;
        __syncthreads(); sc[t] += x; __syncthreads();
    }
    if (t < nb) sums[t] = sc[t] - v;     // exclusive
}

__global__ __launch_bounds__(256) void scan_pass3(const int* __restrict__ cnt,
                                                  const int* __restrict__ sums,
                                                  int* __restrict__ row_ptr) {
    __shared__ int sc[256];
    int b = blockIdx.x, t = threadIdx.x;
    int base = b * 1024 + t * 4;
    int e[4]; int v = 0;
    #pragma unroll
    for (int i = 0; i < 4; ++i) { int idx = base + i; e[i] = (idx < NSEG) ? cnt[idx] : 0; v += e[i]; }
    sc[t] = v; __syncthreads();
    for (int off = 1; off < 256; off <<= 1) {
        int x = (t >= off) ? sc[t - off] : 0;
        __syncthreads(); sc[t] += x; __syncthreads();
    }
    int run = sums[b] + (sc[t] - v);
    #pragma unroll
    for (int i = 0; i < 4; ++i) {
        int idx = base + i;
        if (idx < NSEG) row_ptr[idx] = run;
        run += e[i];
    }
    if (b == 0 && t == 0) row_ptr[NSEG] = N_EDGES;
}

// cnt doubles as the placement cursor (atomicSub); cnt is dead afterwards.
__global__ void place_edges(const int* __restrict__ src, const int* __restrict__ dst,
                            const int* __restrict__ et, const int* __restrict__ row_ptr,
                            int* __restrict__ cnt, int* __restrict__ sorted) {
    int e = blockIdx.x * 256 + threadIdx.x;
    if (e >= N_EDGES) return;
    int r = et[e];
    int key = dst[e] * N_REL + r;
    int old = atomicSub(&cnt[key], 1);
    int r0 = row_ptr[key];
    int c = row_ptr[key + 1] - r0;                 // |N_r(dst)| for this segment
    sorted[r0 + old - 1] = src[e] | (r << 17) | (c << 20);
}

// ---------------- weight pack (all 4 layers in ONE launch, range-dispatched) ----------------
// BT[col][k] bf16, col = r*O+o (r=8 -> root), zero-pad cols to NPAD.
// Ranges: L1 2304x128=294912 | L2/L3 2304x256=589824 each | L4 640x256=163840.
__global__ void convert_weights_all(const float* __restrict__ W1, const float* __restrict__ R1, ushort* __restrict__ B1,
                                    const float* __restrict__ W2, const float* __restrict__ R2, ushort* __restrict__ B2,
                                    const float* __restrict__ W3, const float* __restrict__ R3, ushort* __restrict__ B3,
                                    const float* __restrict__ W4, const float* __restrict__ R4, ushort* __restrict__ B4) {
    int idx = blockIdx.x * 256 + threadIdx.x;
    const float* W; const float* root; ushort* BT; int K, O;
    if (idx < 294912)       { W = W1; root = R1; BT = B1; K = 128; O = 256; }
    else if (idx < 884736)  { W = W2; root = R2; BT = B2; K = 256; O = 256; idx -= 294912; }
    else if (idx < 1474560) { W = W3; root = R3; BT = B3; K = 256; O = 256; idx -= 884736; }
    else if (idx < 1638400) { W = W4; root = R4; BT = B4; K = 256; O = 64;  idx -= 1474560; }
    else return;
    int col = idx / K, i = idx % K;
    float v = 0.0f;
    if (col < N_REL * O) {
        int r = col / O, o = col % O;
        v = W[((size_t)r * K + i) * O + o];
    } else if (col < (N_REL + 1) * O) {
        v = root[(size_t)i * O + (col - N_REL * O)];
    }
    BT[idx] = f2bf(v);
}

// ---------------- bf16 MFMA GEMM: 2-phase double-buffered k-loop (round-4 proven) ----------------
// Double 16 KB LDS buffers; per step ISSUE next tile's global_load_lds, THEN compute
// current tile, THEN one __syncthreads (its implicit vmcnt(0) waits on loads that had
// the whole MFMA phase in flight). XOR chunk swizzle both-sides (rule #21). Epilogue:
// two-pass transpose -> full-line 128 B stores.
template<int K, int CTS, int NW>
__global__ __launch_bounds__(256)
void gemm_mfma(const ushort* __restrict__ A, const ushort* __restrict__ BT,
               ushort* __restrict__ Y) {
    // ---- swizzle: f -> (stripe y, col-tile ct) pinned to XCD f&7 ----
    const int f = blockIdx.x;
    const int g = f & 7, m = f >> 3;
    const int y = g + 8 * (m / CTS);
    const int ct = m % CTS;
    if (y >= NSTRIPE) return;               // uniform early-exit (before any barrier)
    const int row0 = y * 128;
    const int col0 = ct * 128;

    __shared__ ushort SMEM[16384];          // 32 KB: 2 x (As|Bs 16 KB); epilogue Ts aliases head
    const int t = threadIdx.x;
    const int lane = t & 63;
    const int w = t >> 6;
    const int l16 = lane & 15, q = lane >> 4;
    const int wm = (w & 1) * 64, wn = (w >> 1) * 64;

    const int c0i = w * 64 + lane;
    const int c1i = c0i + 256;
    const int r0i = c0i >> 2, r1i = c1i >> 2;
    const int j0i = (c0i & 3) ^ ((r0i >> 1) & 3);
    const int j1i = (c1i & 3) ^ ((r1i >> 1) & 3);
    const size_t ga0 = (size_t)r0i * K + (size_t)j0i * 8;
    const size_t ga1 = (size_t)r1i * K + (size_t)j1i * 8;
    const ushort* Ab = A + (size_t)row0 * K;
    const ushort* Bb = BT + (size_t)col0 * K;

    const int qx = (q ^ ((l16 >> 1) & 3)) * 8;   // un-swizzle chunk on LDS read

    f32x4 acc[4][4] = {};

    auto STAGE = [&](int b, int k0) {
        ushort* As = SMEM + b * 8192;
        ushort* Bs = As + 4096;
        async16(Ab + k0 + ga0, &As[w * 512]);
        async16(Ab + k0 + ga1, &As[(w + 4) * 512]);
        async16(Bb + k0 + ga0, &Bs[w * 512]);
        async16(Bb + k0 + ga1, &Bs[(w + 4) * 512]);
    };
    auto COMPUTE = [&](int b) {
        ushort* As = SMEM + b * 8192;
        ushort* Bs = As + 4096;
        bf16x8 a[4], bb[4];
        #pragma unroll
        for (int i = 0; i < 4; ++i) {
            a[i]  = *(const bf16x8*)&As[(wm + i * 16 + l16) * 32 + qx];
            bb[i] = *(const bf16x8*)&Bs[(wn + i * 16 + l16) * 32 + qx];
        }
        #pragma unroll
        for (int i = 0; i < 4; ++i)
            #pragma unroll
            for (int j = 0; j < 4; ++j)
                acc[i][j] = __builtin_amdgcn_mfma_f32_16x16x32_bf16(a[i], bb[j], acc[i][j], 0, 0, 0);
    };

    constexpr int NSTEP = K / 32;
    STAGE(0, 0);
    __syncthreads();                        // prologue drain (first tile staged)
    #pragma unroll
    for (int s = 0; s < NSTEP; ++s) {
        if (s + 1 < NSTEP) STAGE((s + 1) & 1, 32 * (s + 1));   // prefetch next tile
        COMPUTE(s & 1);                                         // compute current
        __syncthreads();   // implicit vmcnt(0): next tile landed (hidden under MFMA)
    }

    // ---- epilogue: two-pass transpose via wave-private LDS (32 rows x stride 72),
    // then full-line stores: 8 lanes cover 128 B of one row per instruction.
    ushort* Ts = &SMEM[w * 32 * 72];
    const int rr = lane >> 3;               // 0..7 row within 8-row group
    const int cc = (lane & 7) * 8;          // 16B chunk within row
    #pragma unroll
    for (int half = 0; half < 2; ++half) {
        // scatter: D mapping col=l16, row=q*4+reg (verified gfx950 layout)
        #pragma unroll
        for (int i = 0; i < 2; ++i)
            #pragma unroll
            for (int j = 0; j < 4; ++j)
                #pragma unroll
                for (int r = 0; r < 4; ++r)
                    Ts[(i * 16 + q * 4 + r) * 72 + j * 16 + l16] = f2bf(acc[half * 2 + i][j][r]);
        // gather+store (wave-private region; compiler orders LDS ops via lgkmcnt)
        #pragma unroll
        for (int p = 0; p < 4; ++p) {
            int row = p * 8 + rr;           // 0..31 local
            uint4 v = *(const uint4*)&Ts[row * 72 + cc];
            *(uint4*)(Y + (size_t)(row0 + wm + half * 32 + row) * NW + col0 + wn + cc) = v;
        }
    }
}

// ---------------- fused gather: out[d] = act( root + bias + sum_e w_e * Y[src_e, rel_e*O+c] ) ----------------
// dst-major sort: one contiguous edge run per dst; weight = 1/count decoded from the
// packed entry. 8-wide unrolled flat loop (round-10 proven MLP depth).
template<int O>
__global__ __launch_bounds__(256)
void gather_kernel(const ushort* __restrict__ Y, int NW,
                   const int* __restrict__ row_ptr, const int* __restrict__ sorted,
                   const float* __restrict__ bias,
                   float* __restrict__ out_f32, ushort* __restrict__ out_bf16, int relu) {
    constexpr int TPN = O / 8;
    int d = blockIdx.x * (256 / TPN) + threadIdx.x / TPN;
    if (d >= N_NODES) return;
    int c0 = (threadIdx.x % TPN) * 8;
    int p0 = row_ptr[d * N_REL];
    int p1 = row_ptr[d * N_REL + N_REL];
    float sum[8] = {};
    add8(sum, *(const uint4*)(Y + (size_t)d * NW + N_REL * O + c0));   // root slice
    #pragma unroll
    for (int k = 0; k < 8; ++k) sum[k] += bias[c0 + k];
    const ushort* Yc = Y + c0;
    #define EDGE_LD(sx) (*(const uint4*)(Yc + (size_t)((sx) & 0x1FFFF) * NW + ((((sx) >> 17) & 7) * O)))
    #define EDGE_W(sx)  (1.0f / (float)((unsigned)(sx) >> 20))
    int e = p0;
    for (; e + 8 <= p1; e += 8) {
        int s0 = sorted[e],     s1 = sorted[e + 1], s2 = sorted[e + 2], s3 = sorted[e + 3];
        int s4 = sorted[e + 4], s5 = sorted[e + 5], s6 = sorted[e + 6], s7 = sorted[e + 7];
        uint4 v0 = EDGE_LD(s0);
        uint4 v1 = EDGE_LD(s1);
        uint4 v2 = EDGE_LD(s2);
        uint4 v3 = EDGE_LD(s3);
        uint4 v4 = EDGE_LD(s4);
        uint4 v5 = EDGE_LD(s5);
        uint4 v6 = EDGE_LD(s6);
        uint4 v7 = EDGE_LD(s7);
        fma8(sum, v0, EDGE_W(s0));
        fma8(sum, v1, EDGE_W(s1));
        fma8(sum, v2, EDGE_W(s2));
        fma8(sum, v3, EDGE_W(s3));
        fma8(sum, v4, EDGE_W(s4));
        fma8(sum, v5, EDGE_W(s5));
        fma8(sum, v6, EDGE_W(s6));
        fma8(sum, v7, EDGE_W(s7));
    }
    if (e + 4 <= p1) {
        int s0 = sorted[e], s1 = sorted[e + 1], s2 = sorted[e + 2], s3 = sorted[e + 3];
        uint4 v0 = EDGE_LD(s0);
        uint4 v1 = EDGE_LD(s1);
        uint4 v2 = EDGE_LD(s2);
        uint4 v3 = EDGE_LD(s3);
        fma8(sum, v0, EDGE_W(s0));
        fma8(sum, v1, EDGE_W(s1));
        fma8(sum, v2, EDGE_W(s2));
        fma8(sum, v3, EDGE_W(s3));
        e += 4;
    }
    for (; e < p1; ++e) {
        int s = sorted[e];
        uint4 v = EDGE_LD(s);
        fma8(sum, v, EDGE_W(s));
    }
    #undef EDGE_LD
    #undef EDGE_W
    if (relu) {
        #pragma unroll
        for (int k = 0; k < 8; ++k) sum[k] = fmaxf(sum[k], 0.0f);
    }
    if (out_bf16) {
        ushort o[8];
        #pragma unroll
        for (int k = 0; k < 8; ++k) o[k] = f2bf(sum[k]);
        *(uint4*)(out_bf16 + (size_t)d * O + c0) = *(const uint4*)o;
    } else {
        float* p = out_f32 + (size_t)d * O + c0;
        *(float4*)p = make_float4(sum[0], sum[1], sum[2], sum[3]);
        *(float4*)(p + 4) = make_float4(sum[4], sum[5], sum[6], sum[7]);
    }
}

// ---------------- host side ----------------

extern "C" void kernel_launch(void* const* d_in, const int* in_sizes, int n_in,
                              void* d_out, int out_size, void* d_ws, size_t ws_size,
                              hipStream_t stream) {
    const float* x  = (const float*)d_in[0];
    const int*   ei = (const int*)d_in[1];
    const int*   et = (const int*)d_in[2];
    const float* W[4]  = {(const float*)d_in[3], (const float*)d_in[6], (const float*)d_in[9],  (const float*)d_in[12]};
    const float* RT[4] = {(const float*)d_in[4], (const float*)d_in[7], (const float*)d_in[10], (const float*)d_in[13]};
    const float* BI[4] = {(const float*)d_in[5], (const float*)d_in[8], (const float*)d_in[11], (const float*)d_in[14]};
    const int KS[4] = {128, 256, 256, 256};
    const int NP[4] = {2304, 2304, 2304, 640};   // packed+padded BT rows (= Y width)
    const int* src = ei;
    const int* dst = ei + N_EDGES;

    // ---- workspace carve-up (proven round-4/10 layout) ----
    char* ws = (char*)d_ws;
    size_t off = 0;
    auto take = [&](size_t bytes) -> char* {
        char* p = ws + off;
        off = (off + bytes + 255) & ~(size_t)255;
        return p;
    };
    int* row_ptr    = (int*)take((size_t)(NSEG + 1) * 4);
    int* sorted     = (int*)take((size_t)N_EDGES * 4);
    ushort* BTp[4];
    for (int l = 0; l < 4; ++l) BTp[l] = (ushort*)take((size_t)NP[l] * KS[l] * 2);
    ushort* hb = (ushort*)take((size_t)N_PAD * 256 * 2);
    ushort* Yb = (ushort*)take((size_t)N_PAD * 2304 * 2);
    // cnt + sums alias the head of Yb: dead before the first GEMM writes Yb
    // (strict stream order).
    int* cnt  = (int*)Yb;
    int* sums = (int*)((char*)Yb + (size_t)NSEG * 4);

    // ---- preprocessing: 7 launches (was 11; ~4 us/launch overhead) ----
    hipMemsetAsync(cnt, 0, (size_t)NSEG * 4, stream);
    f2bf_and_count<<<(N_NODES * 128 / 4 + 255) / 256, 256, 0, stream>>>(
        x, hb, N_NODES * 128 / 4, dst, et, cnt);
    scan_pass1<<<SCAN_NB, 256, 0, stream>>>(cnt, sums);
    scan_pass2<<<1, 512, 0, stream>>>(sums, SCAN_NB);
    scan_pass3<<<SCAN_NB, 256, 0, stream>>>(cnt, sums, row_ptr);
    place_edges<<<(N_EDGES + 255) / 256, 256, 0, stream>>>(src, dst, et, row_ptr, cnt, sorted);
    convert_weights_all<<<(1638400 + 255) / 256, 256, 0, stream>>>(
        W[0], RT[0], BTp[0], W[1], RT[1], BTp[1],
        W[2], RT[2], BTp[2], W[3], RT[3], BTp[3]);

    // ---- 4 layers: XCD-swizzled GEMM + fused gather ----
    const int G18 = 8 * SPX * 18;   // 7056
    const int G5  = 8 * SPX * 5;    // 1960
    gemm_mfma<128, 18, 2304><<<G18, 256, 0, stream>>>(hb, BTp[0], Yb);
    gather_kernel<256><<<dim3((N_NODES + 7) / 8), 256, 0, stream>>>(
        Yb, 2304, row_ptr, sorted, BI[0], nullptr, hb, 1);

    gemm_mfma<256, 18, 2304><<<G18, 256, 0, stream>>>(hb, BTp[1], Yb);
    gather_kernel<256><<<dim3((N_NODES + 7) / 8), 256, 0, stream>>>(
        Yb, 2304, row_ptr, sorted, BI[1], nullptr, hb, 1);

    gemm_mfma<256, 18, 2304><<<G18, 256, 0, stream>>>(hb, BTp[2], Yb);
    gather_kernel<256><<<dim3((N_NODES + 7) / 8), 256, 0, stream>>>(
        Yb, 2304, row_ptr, sorted, BI[2], nullptr, hb, 1);

    gemm_mfma<256, 5, 640><<<G5, 256, 0, stream>>>(hb, BTp[3], Yb);
    gather_kernel<64><<<dim3((N_NODES + 31) / 32), 256, 0, stream>>>(
        Yb, 640, row_ptr, sorted, BI[3], (float*)d_out, nullptr, 0);
}